// Round 5
// baseline (2041.907 us; speedup 1.0000x reference)
//
#include <hip/hip_runtime.h>

#define NN 100000
#define EE 3200000
#define DD 256
#define CC 40
#define NCH 16
#define CH 16
#define UN2 8

#define HALF_BLOCKS 2048
#define CHUNK_BLOCKS (2 * HALF_BLOCKS)
#define COHORT 256            // blocks per chunk
#define RG_PER_CHUNK 3125     // 100000 / 32 row-groups of 32 rows

__device__ __forceinline__ float bf2f(unsigned int u) {
    return __uint_as_float(u << 16);
}
__device__ __forceinline__ unsigned short f2bf(float f) {
    unsigned int t = __float_as_uint(f);
    return (unsigned short)((t + 0x7FFFu + ((t >> 16) & 1u)) >> 16);
}

// ---------------- CSR row_ptr from sorted adj_row ----------------
__global__ __launch_bounds__(256) void k_row_ptr(const int* __restrict__ adj_row,
                                                 int* __restrict__ row_ptr) {
    int e = blockIdx.x * 256 + threadIdx.x;
    if (e >= EE) return;
    int r = adj_row[e];
    int prev = (e == 0) ? -1 : adj_row[e - 1];
    for (int rr = prev + 1; rr <= r; ++rr) row_ptr[rr] = e;
    if (e == EE - 1) {
        for (int rr = r + 1; rr <= NN; ++rr) row_ptr[rr] = EE;
    }
}

// ---- x[NN][256] f32 -> xb[16][NN][16] bf16, LDS transpose, coalesced IO ----
// 32 rows per block, 3125 blocks exactly.
__global__ __launch_bounds__(256) void k_cvt_t(const float* __restrict__ x,
                                               ushort* __restrict__ xb) {
    __shared__ ushort ls[32][DD + 4];   // +4 ushorts: 2-row stride = 4 banks
    int t = threadIdx.x;
    size_t r0 = (size_t)blockIdx.x * 32;
    const float4* src = (const float4*)(x + r0 * DD);
#pragma unroll
    for (int u = 0; u < 8; ++u) {
        int idx = u * 256 + t;          // coalesced float4 stream
        float4 v = src[idx];
        int row = idx >> 6, d4 = idx & 63;
        ushort* p = &ls[row][d4 * 4];
        p[0] = f2bf(v.x); p[1] = f2bf(v.y); p[2] = f2bf(v.z); p[3] = f2bf(v.w);
    }
    __syncthreads();
    // thread t: chunk c = t>>4 (lane-high -> coalesced global), row pair rp
    int c = t >> 4, rp = t & 15;
    const uint4* s0 = (const uint4*)&ls[2 * rp][c * CH];
    const uint4* s1 = (const uint4*)&ls[2 * rp + 1][c * CH];
    uint4* dst = (uint4*)(xb + ((size_t)c * NN + r0 + 2 * rp) * CH);
    dst[0] = s0[0];
    dst[1] = s0[1];
    dst[2] = s1[0];   // row 2rp+1 is contiguous after row 2rp in xb
    dst[3] = s1[1];
}

// ---- chunked SpMM1 + relu + dropout -> hb (bf16 row-major), NO reduction ----
// Wave = 8 rows x 8 lane-pairs(2 dims). acc per lane IS h[row][dim] -> no
// cross-lane tree. chunk c pinned to XCD via blockIdx%8; blocks 0..2047 do
// chunks 0-7, 2048..4095 do 8-15 (one 3.2MB chunk per XCD L2 at a time).
__global__ __launch_bounds__(256) void k_chunk(
    const ushort* __restrict__ xb, const float* __restrict__ adj_vals,
    const int* __restrict__ adj_col, const int* __restrict__ row_ptr,
    const float* __restrict__ drop_mask, ushort* __restrict__ hb)
{
    int bid = blockIdx.x;
    int half = (bid >= HALF_BLOCKS) ? 1 : 0;
    int rem = bid - half * HALF_BLOCKS;
    int c = (rem & 7) + half * 8;
    int q = rem >> 3;                       // cohort rank 0..255
    int wave = threadIdx.x >> 6, lane = threadIdx.x & 63;
    int g = lane >> 3, i = lane & 7;        // row-in-octet, dim-pair
    const ushort* xc = xb + (size_t)c * NN * CH;

    for (int rg = q; rg < RG_PER_CHUNK; rg += COHORT) {
        int row = rg * 32 + wave * 8 + g;
        int e0 = row_ptr[row];
        int cnt = row_ptr[row + 1] - e0;
        int mc = cnt;                        // max count across the 8 rows
        mc = max(mc, __shfl_xor(mc, 8));
        mc = max(mc, __shfl_xor(mc, 16));
        mc = max(mc, __shfl_xor(mc, 32));
        float ax = 0.f, ay = 0.f;
        for (int k = 0; k < mc; k += UN2) {
            float vv[UN2]; int col[UN2];
#pragma unroll
            for (int u = 0; u < UN2; ++u) {
                int kk = k + u;
                int idx = e0 + max(0, min(kk, cnt - 1));
                float v = __builtin_nontemporal_load(adj_vals + idx);
                col[u] = __builtin_nontemporal_load(adj_col + idx);
                vv[u] = (kk < cnt) ? v : 0.f;
            }
            unsigned xv[UN2];
#pragma unroll
            for (int u = 0; u < UN2; ++u)
                xv[u] = *(const unsigned*)(xc + (size_t)col[u] * CH + i * 2);
#pragma unroll
            for (int u = 0; u < UN2; ++u) {
                ax = fmaf(vv[u], bf2f(xv[u] & 0xFFFFu), ax);
                ay = fmaf(vv[u], bf2f(xv[u] >> 16), ay);
            }
        }
        size_t off = (size_t)row * DD + c * CH + i * 2;
        float m0 = __builtin_nontemporal_load(drop_mask + off);
        float m1 = __builtin_nontemporal_load(drop_mask + off + 1);
        float h0 = fmaxf(ax, 0.f) * m0 * 2.f;
        float h1 = fmaxf(ay, 0.f) * m1 * 2.f;
        unsigned pk = (unsigned)f2bf(h0) | ((unsigned)f2bf(h1) << 16);
        __builtin_nontemporal_store(pk, (unsigned*)(hb + off));
    }
}

// ---------- Linear(256->40): z = h @ W^T + b, h bf16 row-major ----------
__global__ __launch_bounds__(256) void k_linear(
    const ushort* __restrict__ hb, const float* __restrict__ W,
    const float* __restrict__ b, float* __restrict__ z)
{
    __shared__ float hs[4][DD];
    int wave = threadIdx.x >> 6, lane = threadIdx.x & 63;
    int row = blockIdx.x * 4 + wave;
    if (lane < 32) {
        uint4 d = *(const uint4*)(hb + (size_t)row * DD + lane * 8);
        float* hw = hs[wave] + lane * 8;
        hw[0] = bf2f(d.x & 0xFFFFu); hw[1] = bf2f(d.x >> 16);
        hw[2] = bf2f(d.y & 0xFFFFu); hw[3] = bf2f(d.y >> 16);
        hw[4] = bf2f(d.z & 0xFFFFu); hw[5] = bf2f(d.z >> 16);
        hw[6] = bf2f(d.w & 0xFFFFu); hw[7] = bf2f(d.w >> 16);
    }
    __syncthreads();
    if (lane < CC) {
        const float4* wr = (const float4*)(W + (size_t)lane * DD);
        const float4* hv = (const float4*)hs[wave];
        float4 p = {0.f, 0.f, 0.f, 0.f};
#pragma unroll 8
        for (int k = 0; k < DD / 4; ++k) {
            float4 wk = wr[k];
            float4 hk = hv[k];
            p.x = fmaf(hk.x, wk.x, p.x);
            p.y = fmaf(hk.y, wk.y, p.y);
            p.z = fmaf(hk.z, wk.z, p.z);
            p.w = fmaf(hk.w, wk.w, p.w);
        }
        z[(size_t)row * CC + lane] = p.x + p.y + p.z + p.w + b[lane];
    }
}

// ---------------- out = SpMM(z), z [NN,40] f32 (cache-hot) ----------------
__global__ __launch_bounds__(256) void k_spmm2(
    const float* __restrict__ z, const float* __restrict__ adj_vals,
    const int* __restrict__ adj_col, const int* __restrict__ row_ptr,
    float* __restrict__ out)
{
    int wave = threadIdx.x >> 6;
    int lane = threadIdx.x & 63;
    int row = blockIdx.x * 4 + wave;
    int cl = lane < CC ? lane : CC - 1;

    int e0 = __builtin_amdgcn_readfirstlane(row_ptr[row]);
    int e1 = __builtin_amdgcn_readfirstlane(row_ptr[row + 1]);

    float acc = 0.f;
    int nb = (e1 - e0 + UN2 - 1) / UN2;
    for (int bI = 0; bI < nb; ++bI) {
        int base = e0 + bI * UN2;
        float vv[UN2]; int cc[UN2];
#pragma unroll
        for (int u = 0; u < UN2; ++u) {
            int idx = base + u;
            bool ok = idx < e1;
            idx = ok ? idx : e1 - 1;
            vv[u] = ok ? adj_vals[idx] : 0.f;
            cc[u] = adj_col[idx];
        }
        float za[UN2];
#pragma unroll
        for (int u = 0; u < UN2; ++u)
            za[u] = z[(size_t)cc[u] * CC + cl];
#pragma unroll
        for (int u = 0; u < UN2; ++u)
            acc = fmaf(vv[u], za[u], acc);
    }
    if (lane < CC) out[(size_t)row * CC + lane] = acc;
}

extern "C" void kernel_launch(void* const* d_in, const int* in_sizes, int n_in,
                              void* d_out, int out_size, void* d_ws, size_t ws_size,
                              hipStream_t stream) {
    const float* x         = (const float*)d_in[0];
    const float* adj_vals  = (const float*)d_in[1];
    const float* W         = (const float*)d_in[2];
    const float* b         = (const float*)d_in[3];
    const float* drop_mask = (const float*)d_in[4];
    const int*   adj_row   = (const int*)d_in[5];
    const int*   adj_col   = (const int*)d_in[6];
    float* out = (float*)d_out;

    // ws: row_ptr | z | xb[16][NN][16] | hb[NN][256]   (~119 MB)
    char* wsp = (char*)d_ws;
    size_t rp_bytes = ((size_t)(NN + 1) * 4 + 255) & ~(size_t)255;
    size_t z_bytes  = (size_t)NN * CC * 4;
    size_t xb_bytes = (size_t)NN * DD * 2;
    int* row_ptr = (int*)wsp;
    float* zbuf  = (float*)(wsp + rp_bytes);
    ushort* xb   = (ushort*)(wsp + rp_bytes + z_bytes);
    ushort* hb   = (ushort*)(wsp + rp_bytes + z_bytes + xb_bytes);

    hipLaunchKernelGGL(k_row_ptr, dim3((EE + 255) / 256), dim3(256), 0, stream,
                       adj_row, row_ptr);
    hipLaunchKernelGGL(k_cvt_t, dim3(NN / 32), dim3(256), 0, stream, x, xb);
    hipLaunchKernelGGL(k_chunk, dim3(CHUNK_BLOCKS), dim3(256), 0, stream,
                       xb, adj_vals, adj_col, row_ptr, drop_mask, hb);
    hipLaunchKernelGGL(k_linear, dim3(NN / 4), dim3(256), 0, stream,
                       hb, W, b, zbuf);
    hipLaunchKernelGGL(k_spmm2, dim3(NN / 4), dim3(256), 0, stream,
                       zbuf, adj_vals, adj_col, row_ptr, out);
}

// Round 7
// 1062.868 us; speedup vs baseline: 1.9211x; 1.9211x over previous
//
#include <hip/hip_runtime.h>

#define NN 100000
#define EE 3200000
#define DD 256
#define CC 40
#define NCH 16
#define CH 16
#define UN2 8

#define CAP 3072              // staged edges per 64-row group (avg 2048, +16 sigma)
#define ROWS_PB 64
#define COHORT 192            // blocks per chunk
#define HALFB (COHORT * 8)    // 1536
#define CHUNK_BLOCKS (2 * HALFB)
#define RG64 1563             // ceil(NN / 64)

__device__ __forceinline__ float bf2f(unsigned int u) {
    return __uint_as_float(u << 16);
}
__device__ __forceinline__ unsigned short f2bf(float f) {
    unsigned int t = __float_as_uint(f);
    return (unsigned short)((t + 0x7FFFu + ((t >> 16) & 1u)) >> 16);
}

// ---------------- CSR row_ptr from sorted adj_row ----------------
__global__ __launch_bounds__(256) void k_row_ptr(const int* __restrict__ adj_row,
                                                 int* __restrict__ row_ptr) {
    int e = blockIdx.x * 256 + threadIdx.x;
    if (e >= EE) return;
    int r = adj_row[e];
    int prev = (e == 0) ? -1 : adj_row[e - 1];
    for (int rr = prev + 1; rr <= r; ++rr) row_ptr[rr] = e;
    if (e == EE - 1) {
        for (int rr = r + 1; rr <= NN; ++rr) row_ptr[rr] = EE;
    }
}

// ---- x[NN][256] f32 -> xb[16][NN][16] bf16, LDS transpose, coalesced IO ----
__global__ __launch_bounds__(256) void k_cvt_t(const float* __restrict__ x,
                                               ushort* __restrict__ xb) {
    __shared__ ushort ls[32][DD + 4];
    int t = threadIdx.x;
    size_t r0 = (size_t)blockIdx.x * 32;
    const float4* src = (const float4*)(x + r0 * DD);
#pragma unroll
    for (int u = 0; u < 8; ++u) {
        int idx = u * 256 + t;
        float4 v = src[idx];
        int row = idx >> 6, d4 = idx & 63;
        ushort* p = &ls[row][d4 * 4];
        p[0] = f2bf(v.x); p[1] = f2bf(v.y); p[2] = f2bf(v.z); p[3] = f2bf(v.w);
    }
    __syncthreads();
    int c = t >> 4, rp = t & 15;
    const uint4* s0 = (const uint4*)&ls[2 * rp][c * CH];
    const uint4* s1 = (const uint4*)&ls[2 * rp + 1][c * CH];
    uint4* dst = (uint4*)(xb + ((size_t)c * NN + r0 + 2 * rp) * CH);
    dst[0] = s0[0];
    dst[1] = s0[1];
    dst[2] = s1[0];
    dst[3] = s1[1];
}

// ---- chunked SpMM1 + relu + dropout -> hb, reduction-free, LDS metadata ----
// Block = one chunk c (pinned to XCD via bid%8) x 64-row groups (strided by
// COHORT). Per group: stage the contiguous edge range [row_ptr[row0],
// row_ptr[row0+64]) into LDS coalesced (full-sector nt), then wave = 16 rows
// x 4 dim-lanes (8B x-gather per lane) accumulates without any cross-lane
// reduction.
__global__ __launch_bounds__(256, 6) void k_chunk(
    const ushort* __restrict__ xb, const float* __restrict__ adj_vals,
    const int* __restrict__ adj_col, const int* __restrict__ row_ptr,
    const float* __restrict__ drop_mask, ushort* __restrict__ hb)
{
    __shared__ uint2 meta[CAP + 8];
    int bid = blockIdx.x;
    int half = (bid >= HALFB) ? 1 : 0;
    int rem = bid - half * HALFB;
    int c = (rem & 7) + half * 8;
    int q = rem >> 3;
    int wave = threadIdx.x >> 6, lane = threadIdx.x & 63;
    int g = lane >> 2, i = lane & 3;        // row-in-16, dim-quad
    const ushort* xc = xb + (size_t)c * NN * CH;

    for (int rg = q; rg < RG64; rg += COHORT) {
        int row0 = rg * ROWS_PB;
        int row  = row0 + wave * 16 + g;
        bool rv  = row < NN;
        int rend = min(row0 + ROWS_PB, NN);
        int e_start = __builtin_amdgcn_readfirstlane(row_ptr[row0]);
        int e_end   = __builtin_amdgcn_readfirstlane(row_ptr[rend]);
        int nstage  = min(e_end - e_start, CAP);

        for (int t = threadIdx.x; t < nstage; t += 256) {
            uint2 m;
            m.x = (unsigned)__builtin_nontemporal_load(adj_col + e_start + t);
            m.y = __float_as_uint(__builtin_nontemporal_load(adj_vals + e_start + t));
            meta[t] = m;
        }
        __syncthreads();

        int e0  = rv ? row_ptr[row] : 0;
        int cnt = rv ? row_ptr[row + 1] - e0 : 0;
        int eloc = e0 - e_start;
        float a0 = 0.f, a1 = 0.f, a2 = 0.f, a3 = 0.f;

        if (eloc + cnt <= nstage) {          // staged path (always, in practice)
            int body = cnt & ~(UN2 - 1);
            int k = 0;
            for (; k < body; k += UN2) {
                uint2 mm[UN2];
#pragma unroll
                for (int u = 0; u < UN2; ++u) mm[u] = meta[eloc + k + u];
                uint2 xv[UN2];
#pragma unroll
                for (int u = 0; u < UN2; ++u)
                    xv[u] = *(const uint2*)(xc + (size_t)mm[u].x * CH + i * 4);
#pragma unroll
                for (int u = 0; u < UN2; ++u) {
                    float v = __uint_as_float(mm[u].y);
                    a0 = fmaf(v, bf2f(xv[u].x & 0xFFFFu), a0);
                    a1 = fmaf(v, bf2f(xv[u].x >> 16),     a1);
                    a2 = fmaf(v, bf2f(xv[u].y & 0xFFFFu), a2);
                    a3 = fmaf(v, bf2f(xv[u].y >> 16),     a3);
                }
            }
            if (k < cnt) {                   // one clamped tail batch
#pragma unroll
                for (int u = 0; u < UN2; ++u) {
                    int kk = k + u;
                    uint2 m = meta[eloc + min(kk, cnt - 1)];
                    float v = (kk < cnt) ? __uint_as_float(m.y) : 0.f;
                    uint2 xv = *(const uint2*)(xc + (size_t)m.x * CH + i * 4);
                    a0 = fmaf(v, bf2f(xv.x & 0xFFFFu), a0);
                    a1 = fmaf(v, bf2f(xv.x >> 16),     a1);
                    a2 = fmaf(v, bf2f(xv.y & 0xFFFFu), a2);
                    a3 = fmaf(v, bf2f(xv.y >> 16),     a3);
                }
            }
        } else {                             // overflow fallback (never, stats-wise)
            for (int k = 0; k < cnt; ++k) {
                int idx = e0 + k;
                float v = adj_vals[idx];
                int col = adj_col[idx];
                uint2 xv = *(const uint2*)(xc + (size_t)col * CH + i * 4);
                a0 = fmaf(v, bf2f(xv.x & 0xFFFFu), a0);
                a1 = fmaf(v, bf2f(xv.x >> 16),     a1);
                a2 = fmaf(v, bf2f(xv.y & 0xFFFFu), a2);
                a3 = fmaf(v, bf2f(xv.y >> 16),     a3);
            }
        }
        __syncthreads();                     // meta safe to overwrite next iter

        if (rv) {
            size_t off = (size_t)row * DD + c * CH + i * 4;
            float4 m4 = *(const float4*)(drop_mask + off);
            float h0 = fmaxf(a0, 0.f) * m4.x * 2.f;
            float h1 = fmaxf(a1, 0.f) * m4.y * 2.f;
            float h2 = fmaxf(a2, 0.f) * m4.z * 2.f;
            float h3 = fmaxf(a3, 0.f) * m4.w * 2.f;
            unsigned long long pk =
                (unsigned long long)((unsigned)f2bf(h0) | ((unsigned)f2bf(h1) << 16)) |
                ((unsigned long long)((unsigned)f2bf(h2) | ((unsigned)f2bf(h3) << 16)) << 32);
            __builtin_nontemporal_store(pk, (unsigned long long*)(hb + off));
        }
    }
}

// ---------- Linear(256->40): z = h @ W^T + b, h bf16 row-major ----------
__global__ __launch_bounds__(256) void k_linear(
    const ushort* __restrict__ hb, const float* __restrict__ W,
    const float* __restrict__ b, float* __restrict__ z)
{
    __shared__ float hs[4][DD];
    int wave = threadIdx.x >> 6, lane = threadIdx.x & 63;
    int row = blockIdx.x * 4 + wave;
    if (lane < 32) {
        uint4 d = *(const uint4*)(hb + (size_t)row * DD + lane * 8);
        float* hw = hs[wave] + lane * 8;
        hw[0] = bf2f(d.x & 0xFFFFu); hw[1] = bf2f(d.x >> 16);
        hw[2] = bf2f(d.y & 0xFFFFu); hw[3] = bf2f(d.y >> 16);
        hw[4] = bf2f(d.z & 0xFFFFu); hw[5] = bf2f(d.z >> 16);
        hw[6] = bf2f(d.w & 0xFFFFu); hw[7] = bf2f(d.w >> 16);
    }
    __syncthreads();
    if (lane < CC) {
        const float4* wr = (const float4*)(W + (size_t)lane * DD);
        const float4* hv = (const float4*)hs[wave];
        float4 p = {0.f, 0.f, 0.f, 0.f};
#pragma unroll 8
        for (int k = 0; k < DD / 4; ++k) {
            float4 wk = wr[k];
            float4 hk = hv[k];
            p.x = fmaf(hk.x, wk.x, p.x);
            p.y = fmaf(hk.y, wk.y, p.y);
            p.z = fmaf(hk.z, wk.z, p.z);
            p.w = fmaf(hk.w, wk.w, p.w);
        }
        z[(size_t)row * CC + lane] = p.x + p.y + p.z + p.w + b[lane];
    }
}

// ---------------- out = SpMM(z), z [NN,40] f32 (cache-hot) ----------------
__global__ __launch_bounds__(256) void k_spmm2(
    const float* __restrict__ z, const float* __restrict__ adj_vals,
    const int* __restrict__ adj_col, const int* __restrict__ row_ptr,
    float* __restrict__ out)
{
    int wave = threadIdx.x >> 6;
    int lane = threadIdx.x & 63;
    int row = blockIdx.x * 4 + wave;
    int cl = lane < CC ? lane : CC - 1;

    int e0 = __builtin_amdgcn_readfirstlane(row_ptr[row]);
    int e1 = __builtin_amdgcn_readfirstlane(row_ptr[row + 1]);

    float acc = 0.f;
    int nb = (e1 - e0 + UN2 - 1) / UN2;
    for (int bI = 0; bI < nb; ++bI) {
        int base = e0 + bI * UN2;
        float vv[UN2]; int cc[UN2];
#pragma unroll
        for (int u = 0; u < UN2; ++u) {
            int idx = base + u;
            bool ok = idx < e1;
            idx = ok ? idx : e1 - 1;
            vv[u] = ok ? adj_vals[idx] : 0.f;
            cc[u] = adj_col[idx];
        }
        float za[UN2];
#pragma unroll
        for (int u = 0; u < UN2; ++u)
            za[u] = z[(size_t)cc[u] * CC + cl];
#pragma unroll
        for (int u = 0; u < UN2; ++u)
            acc = fmaf(vv[u], za[u], acc);
    }
    if (lane < CC) out[(size_t)row * CC + lane] = acc;
}

extern "C" void kernel_launch(void* const* d_in, const int* in_sizes, int n_in,
                              void* d_out, int out_size, void* d_ws, size_t ws_size,
                              hipStream_t stream) {
    const float* x         = (const float*)d_in[0];
    const float* adj_vals  = (const float*)d_in[1];
    const float* W         = (const float*)d_in[2];
    const float* b         = (const float*)d_in[3];
    const float* drop_mask = (const float*)d_in[4];
    const int*   adj_row   = (const int*)d_in[5];
    const int*   adj_col   = (const int*)d_in[6];
    float* out = (float*)d_out;

    // ws: row_ptr | z | xb[16][NN][16] | hb[NN][256]   (~119 MB)
    char* wsp = (char*)d_ws;
    size_t rp_bytes = ((size_t)(NN + 1) * 4 + 255) & ~(size_t)255;
    size_t z_bytes  = (size_t)NN * CC * 4;
    size_t xb_bytes = (size_t)NN * DD * 2;
    int* row_ptr = (int*)wsp;
    float* zbuf  = (float*)(wsp + rp_bytes);
    ushort* xb   = (ushort*)(wsp + rp_bytes + z_bytes);
    ushort* hb   = (ushort*)(wsp + rp_bytes + z_bytes + xb_bytes);

    hipLaunchKernelGGL(k_row_ptr, dim3((EE + 255) / 256), dim3(256), 0, stream,
                       adj_row, row_ptr);
    hipLaunchKernelGGL(k_cvt_t, dim3(NN / 32), dim3(256), 0, stream, x, xb);
    hipLaunchKernelGGL(k_chunk, dim3(CHUNK_BLOCKS), dim3(256), 0, stream,
                       xb, adj_vals, adj_col, row_ptr, drop_mask, hb);
    hipLaunchKernelGGL(k_linear, dim3(NN / 4), dim3(256), 0, stream,
                       hb, W, b, zbuf);
    hipLaunchKernelGGL(k_spmm2, dim3(NN / 4), dim3(256), 0, stream,
                       zbuf, adj_vals, adj_col, row_ptr, out);
}

// Round 8
// 628.077 us; speedup vs baseline: 3.2510x; 1.6923x over previous
//
#include <hip/hip_runtime.h>

#define NN 100000
#define EE 3200000
#define DD 256
#define CC 40
#define NCH 16
#define CH 16
#define UN2 8

#define CAP 3072              // staged edges per 64-row group (avg 2048, +16 sigma)
#define ROWS_PB 64
#define COHORT 192            // blocks per chunk
#define HALFB (COHORT * 8)    // 1536
#define CHUNK_BLOCKS (2 * HALFB)
#define RG64 1563             // ceil(NN / 64)
#define LROWS 64              // rows per k_linear block

__device__ __forceinline__ float bf2f(unsigned int u) {
    return __uint_as_float(u << 16);
}
__device__ __forceinline__ unsigned short f2bf(float f) {
    unsigned int t = __float_as_uint(f);
    return (unsigned short)((t + 0x7FFFu + ((t >> 16) & 1u)) >> 16);
}

// ---------------- CSR row_ptr from sorted adj_row ----------------
__global__ __launch_bounds__(256) void k_row_ptr(const int* __restrict__ adj_row,
                                                 int* __restrict__ row_ptr) {
    int e = blockIdx.x * 256 + threadIdx.x;
    if (e >= EE) return;
    int r = adj_row[e];
    int prev = (e == 0) ? -1 : adj_row[e - 1];
    for (int rr = prev + 1; rr <= r; ++rr) row_ptr[rr] = e;
    if (e == EE - 1) {
        for (int rr = r + 1; rr <= NN; ++rr) row_ptr[rr] = EE;
    }
}

// ---- x[NN][256] f32 -> xb[16][NN][16] bf16, LDS transpose, coalesced IO ----
__global__ __launch_bounds__(256) void k_cvt_t(const float* __restrict__ x,
                                               ushort* __restrict__ xb) {
    __shared__ ushort ls[32][DD + 4];
    int t = threadIdx.x;
    size_t r0 = (size_t)blockIdx.x * 32;
    const float4* src = (const float4*)(x + r0 * DD);
#pragma unroll
    for (int u = 0; u < 8; ++u) {
        int idx = u * 256 + t;
        float4 v = src[idx];
        int row = idx >> 6, d4 = idx & 63;
        ushort* p = &ls[row][d4 * 4];
        p[0] = f2bf(v.x); p[1] = f2bf(v.y); p[2] = f2bf(v.z); p[3] = f2bf(v.w);
    }
    __syncthreads();
    int c = t >> 4, rp = t & 15;
    const uint4* s0 = (const uint4*)&ls[2 * rp][c * CH];
    const uint4* s1 = (const uint4*)&ls[2 * rp + 1][c * CH];
    uint4* dst = (uint4*)(xb + ((size_t)c * NN + r0 + 2 * rp) * CH);
    dst[0] = s0[0];
    dst[1] = s0[1];
    dst[2] = s1[0];
    dst[3] = s1[1];
}

// ---- chunked SpMM1 + relu + dropout -> hb, reduction-free, LDS metadata ----
__global__ __launch_bounds__(256, 6) void k_chunk(
    const ushort* __restrict__ xb, const float* __restrict__ adj_vals,
    const int* __restrict__ adj_col, const int* __restrict__ row_ptr,
    const float* __restrict__ drop_mask, ushort* __restrict__ hb)
{
    __shared__ uint2 meta[CAP + 8];
    int bid = blockIdx.x;
    int half = (bid >= HALFB) ? 1 : 0;
    int rem = bid - half * HALFB;
    int c = (rem & 7) + half * 8;
    int q = rem >> 3;
    int wave = threadIdx.x >> 6, lane = threadIdx.x & 63;
    int g = lane >> 2, i = lane & 3;        // row-in-16, dim-quad
    const ushort* xc = xb + (size_t)c * NN * CH;

    for (int rg = q; rg < RG64; rg += COHORT) {
        int row0 = rg * ROWS_PB;
        int row  = row0 + wave * 16 + g;
        bool rv  = row < NN;
        int rend = min(row0 + ROWS_PB, NN);
        int e_start = __builtin_amdgcn_readfirstlane(row_ptr[row0]);
        int e_end   = __builtin_amdgcn_readfirstlane(row_ptr[rend]);
        int nstage  = min(e_end - e_start, CAP);

        for (int t = threadIdx.x; t < nstage; t += 256) {
            uint2 m;
            m.x = (unsigned)__builtin_nontemporal_load(adj_col + e_start + t);
            m.y = __float_as_uint(__builtin_nontemporal_load(adj_vals + e_start + t));
            meta[t] = m;
        }
        __syncthreads();

        int e0  = rv ? row_ptr[row] : 0;
        int cnt = rv ? row_ptr[row + 1] - e0 : 0;
        int eloc = e0 - e_start;
        float a0 = 0.f, a1 = 0.f, a2 = 0.f, a3 = 0.f;

        if (eloc + cnt <= nstage) {
            int body = cnt & ~(UN2 - 1);
            int k = 0;
            for (; k < body; k += UN2) {
                uint2 mm[UN2];
#pragma unroll
                for (int u = 0; u < UN2; ++u) mm[u] = meta[eloc + k + u];
                uint2 xv[UN2];
#pragma unroll
                for (int u = 0; u < UN2; ++u)
                    xv[u] = *(const uint2*)(xc + (size_t)mm[u].x * CH + i * 4);
#pragma unroll
                for (int u = 0; u < UN2; ++u) {
                    float v = __uint_as_float(mm[u].y);
                    a0 = fmaf(v, bf2f(xv[u].x & 0xFFFFu), a0);
                    a1 = fmaf(v, bf2f(xv[u].x >> 16),     a1);
                    a2 = fmaf(v, bf2f(xv[u].y & 0xFFFFu), a2);
                    a3 = fmaf(v, bf2f(xv[u].y >> 16),     a3);
                }
            }
            if (k < cnt) {
#pragma unroll
                for (int u = 0; u < UN2; ++u) {
                    int kk = k + u;
                    uint2 m = meta[eloc + min(kk, cnt - 1)];
                    float v = (kk < cnt) ? __uint_as_float(m.y) : 0.f;
                    uint2 xv = *(const uint2*)(xc + (size_t)m.x * CH + i * 4);
                    a0 = fmaf(v, bf2f(xv.x & 0xFFFFu), a0);
                    a1 = fmaf(v, bf2f(xv.x >> 16),     a1);
                    a2 = fmaf(v, bf2f(xv.y & 0xFFFFu), a2);
                    a3 = fmaf(v, bf2f(xv.y >> 16),     a3);
                }
            }
        } else {
            for (int k = 0; k < cnt; ++k) {
                int idx = e0 + k;
                float v = adj_vals[idx];
                int col = adj_col[idx];
                uint2 xv = *(const uint2*)(xc + (size_t)col * CH + i * 4);
                a0 = fmaf(v, bf2f(xv.x & 0xFFFFu), a0);
                a1 = fmaf(v, bf2f(xv.x >> 16),     a1);
                a2 = fmaf(v, bf2f(xv.y & 0xFFFFu), a2);
                a3 = fmaf(v, bf2f(xv.y >> 16),     a3);
            }
        }
        __syncthreads();

        if (rv) {
            size_t off = (size_t)row * DD + c * CH + i * 4;
            float4 m4 = *(const float4*)(drop_mask + off);
            float h0 = fmaxf(a0, 0.f) * m4.x * 2.f;
            float h1 = fmaxf(a1, 0.f) * m4.y * 2.f;
            float h2 = fmaxf(a2, 0.f) * m4.z * 2.f;
            float h3 = fmaxf(a3, 0.f) * m4.w * 2.f;
            unsigned long long pk =
                (unsigned long long)((unsigned)f2bf(h0) | ((unsigned)f2bf(h1) << 16)) |
                ((unsigned long long)((unsigned)f2bf(h2) | ((unsigned)f2bf(h3) << 16)) << 32);
            __builtin_nontemporal_store(pk, (unsigned long long*)(hb + off));
        }
    }
}

// ---- Linear(256->40) as register-tiled GEMM: 64 rows/block, W in LDS ----
// Thread = (row = t>>2, class group = (t&3)*10). Per 4-dim step: 1 h-read
// (broadcast across the 4 row-threads) + 10 conflict-free b128 W-reads
// (cg groups hit disjoint bank quartets with [40][260] padding) + 40 fmas
// into 10 independent accumulators.
__global__ __launch_bounds__(256) void k_linear(
    const ushort* __restrict__ hb, const float* __restrict__ W,
    const float* __restrict__ b, float* __restrict__ z)
{
    __shared__ float ws[CC][DD + 4];
    int t = threadIdx.x;
    for (int idx = t; idx < CC * (DD / 4); idx += 256) {
        int c = idx >> 6, k4 = idx & 63;
        float4 v = ((const float4*)(W + (size_t)c * DD))[k4];
        float* p = &ws[c][k4 * 4];
        p[0] = v.x; p[1] = v.y; p[2] = v.z; p[3] = v.w;
    }
    __syncthreads();

    int row = blockIdx.x * LROWS + (t >> 2);
    int cg = (t & 3) * 10;
    if (row >= NN) return;

    const uint4* hrow = (const uint4*)(hb + (size_t)row * DD);
    float acc[10] = {0.f, 0.f, 0.f, 0.f, 0.f, 0.f, 0.f, 0.f, 0.f, 0.f};

    for (int k8 = 0; k8 < DD / 8; ++k8) {           // 8 dims per iter
        uint4 hv = hrow[k8];
        float h0 = bf2f(hv.x & 0xFFFFu), h1 = bf2f(hv.x >> 16);
        float h2 = bf2f(hv.y & 0xFFFFu), h3 = bf2f(hv.y >> 16);
        float h4 = bf2f(hv.z & 0xFFFFu), h5 = bf2f(hv.z >> 16);
        float h6 = bf2f(hv.w & 0xFFFFu), h7 = bf2f(hv.w >> 16);
#pragma unroll
        for (int j = 0; j < 10; ++j) {
            const float* wp = &ws[cg + j][k8 * 8];
            float4 wa = *(const float4*)wp;
            float4 wb = *(const float4*)(wp + 4);
            acc[j] = fmaf(h0, wa.x, fmaf(h1, wa.y,
                     fmaf(h2, wa.z, fmaf(h3, wa.w, acc[j]))));
            acc[j] = fmaf(h4, wb.x, fmaf(h5, wb.y,
                     fmaf(h6, wb.z, fmaf(h7, wb.w, acc[j]))));
        }
    }
#pragma unroll
    for (int j = 0; j < 10; ++j)
        z[(size_t)row * CC + cg + j] = acc[j] + b[cg + j];
}

// ---------------- out = SpMM(z), z [NN,40] f32 (cache-hot) ----------------
__global__ __launch_bounds__(256) void k_spmm2(
    const float* __restrict__ z, const float* __restrict__ adj_vals,
    const int* __restrict__ adj_col, const int* __restrict__ row_ptr,
    float* __restrict__ out)
{
    int wave = threadIdx.x >> 6;
    int lane = threadIdx.x & 63;
    int row = blockIdx.x * 4 + wave;
    int cl = lane < CC ? lane : CC - 1;

    int e0 = __builtin_amdgcn_readfirstlane(row_ptr[row]);
    int e1 = __builtin_amdgcn_readfirstlane(row_ptr[row + 1]);

    float acc = 0.f;
    int nb = (e1 - e0 + UN2 - 1) / UN2;
    for (int bI = 0; bI < nb; ++bI) {
        int base = e0 + bI * UN2;
        float vv[UN2]; int cc[UN2];
#pragma unroll
        for (int u = 0; u < UN2; ++u) {
            int idx = base + u;
            bool ok = idx < e1;
            idx = ok ? idx : e1 - 1;
            vv[u] = ok ? adj_vals[idx] : 0.f;
            cc[u] = adj_col[idx];
        }
        float za[UN2];
#pragma unroll
        for (int u = 0; u < UN2; ++u)
            za[u] = z[(size_t)cc[u] * CC + cl];
#pragma unroll
        for (int u = 0; u < UN2; ++u)
            acc = fmaf(vv[u], za[u], acc);
    }
    if (lane < CC) out[(size_t)row * CC + lane] = acc;
}

extern "C" void kernel_launch(void* const* d_in, const int* in_sizes, int n_in,
                              void* d_out, int out_size, void* d_ws, size_t ws_size,
                              hipStream_t stream) {
    const float* x         = (const float*)d_in[0];
    const float* adj_vals  = (const float*)d_in[1];
    const float* W         = (const float*)d_in[2];
    const float* b         = (const float*)d_in[3];
    const float* drop_mask = (const float*)d_in[4];
    const int*   adj_row   = (const int*)d_in[5];
    const int*   adj_col   = (const int*)d_in[6];
    float* out = (float*)d_out;

    // ws: row_ptr | z | xb[16][NN][16] | hb[NN][256]   (~119 MB)
    char* wsp = (char*)d_ws;
    size_t rp_bytes = ((size_t)(NN + 1) * 4 + 255) & ~(size_t)255;
    size_t z_bytes  = (size_t)NN * CC * 4;
    size_t xb_bytes = (size_t)NN * DD * 2;
    int* row_ptr = (int*)wsp;
    float* zbuf  = (float*)(wsp + rp_bytes);
    ushort* xb   = (ushort*)(wsp + rp_bytes + z_bytes);
    ushort* hb   = (ushort*)(wsp + rp_bytes + z_bytes + xb_bytes);

    hipLaunchKernelGGL(k_row_ptr, dim3((EE + 255) / 256), dim3(256), 0, stream,
                       adj_row, row_ptr);
    hipLaunchKernelGGL(k_cvt_t, dim3(NN / 32), dim3(256), 0, stream, x, xb);
    hipLaunchKernelGGL(k_chunk, dim3(CHUNK_BLOCKS), dim3(256), 0, stream,
                       xb, adj_vals, adj_col, row_ptr, drop_mask, hb);
    hipLaunchKernelGGL(k_linear, dim3((NN + LROWS - 1) / LROWS), dim3(256), 0,
                       stream, hb, W, b, zbuf);
    hipLaunchKernelGGL(k_spmm2, dim3(NN / 4), dim3(256), 0, stream,
                       zbuf, adj_vals, adj_col, row_ptr, out);
}

// Round 9
// 551.633 us; speedup vs baseline: 3.7016x; 1.1386x over previous
//
#include <hip/hip_runtime.h>

#define NN 100000
#define EE 3200000
#define DD 256
#define CC 40
#define NCH 16
#define CH 16
#define UN2 8

#define CAP 2432              // staged edges per 64-row group (avg 2048, +8.5 sigma)
#define ROWS_PB 64
#define COHORT 192            // blocks per chunk
#define HALFB (COHORT * 8)    // 1536
#define CHUNK_BLOCKS (2 * HALFB)
#define RG64 1563             // ceil(NN / 64)
#define LROWS 64              // rows per k_linear block

__device__ __forceinline__ float bf2f(unsigned int u) {
    return __uint_as_float(u << 16);
}
__device__ __forceinline__ unsigned short f2bf(float f) {
    unsigned int t = __float_as_uint(f);
    return (unsigned short)((t + 0x7FFFu + ((t >> 16) & 1u)) >> 16);
}

// ---------------- CSR row_ptr from sorted adj_row ----------------
__global__ __launch_bounds__(256) void k_row_ptr(const int* __restrict__ adj_row,
                                                 int* __restrict__ row_ptr) {
    int e = blockIdx.x * 256 + threadIdx.x;
    if (e >= EE) return;
    int r = adj_row[e];
    int prev = (e == 0) ? -1 : adj_row[e - 1];
    for (int rr = prev + 1; rr <= r; ++rr) row_ptr[rr] = e;
    if (e == EE - 1) {
        for (int rr = r + 1; rr <= NN; ++rr) row_ptr[rr] = EE;
    }
}

// ---- x[NN][256] f32 -> xb[16][NN][16] bf16, LDS transpose, coalesced IO ----
__global__ __launch_bounds__(256) void k_cvt_t(const float* __restrict__ x,
                                               ushort* __restrict__ xb) {
    __shared__ ushort ls[32][DD + 4];
    int t = threadIdx.x;
    size_t r0 = (size_t)blockIdx.x * 32;
    const float4* src = (const float4*)(x + r0 * DD);
#pragma unroll
    for (int u = 0; u < 8; ++u) {
        int idx = u * 256 + t;
        float4 v = src[idx];
        int row = idx >> 6, d4 = idx & 63;
        ushort* p = &ls[row][d4 * 4];
        p[0] = f2bf(v.x); p[1] = f2bf(v.y); p[2] = f2bf(v.z); p[3] = f2bf(v.w);
    }
    __syncthreads();
    int c = t >> 4, rp = t & 15;
    const uint4* s0 = (const uint4*)&ls[2 * rp][c * CH];
    const uint4* s1 = (const uint4*)&ls[2 * rp + 1][c * CH];
    uint4* dst = (uint4*)(xb + ((size_t)c * NN + r0 + 2 * rp) * CH);
    dst[0] = s0[0];
    dst[1] = s0[1];
    dst[2] = s1[0];
    dst[3] = s1[1];
}

// ---- chunked SpMM1 + relu + dropout -> hb, reduction-free, LDS metadata ----
// Meta staging uses PLAIN loads so the 25.6MB adj arrays stay LLC-resident
// across the 16 chunk passes (NT here forced 410MB of HBM replay in r8).
// drop_mask keeps NT (single-use stream; must not evict meta from LLC).
__global__ __launch_bounds__(256, 8) void k_chunk(
    const ushort* __restrict__ xb, const float* __restrict__ adj_vals,
    const int* __restrict__ adj_col, const int* __restrict__ row_ptr,
    const float* __restrict__ drop_mask, ushort* __restrict__ hb)
{
    __shared__ uint2 meta[CAP + 8];
    int bid = blockIdx.x;
    int half = (bid >= HALFB) ? 1 : 0;
    int rem = bid - half * HALFB;
    int c = (rem & 7) + half * 8;
    int q = rem >> 3;
    int wave = threadIdx.x >> 6, lane = threadIdx.x & 63;
    int g = lane >> 2, i = lane & 3;        // row-in-16, dim-quad
    const ushort* xc = xb + (size_t)c * NN * CH;

    for (int rg = q; rg < RG64; rg += COHORT) {
        int row0 = rg * ROWS_PB;
        int row  = row0 + wave * 16 + g;
        bool rv  = row < NN;
        int rend = min(row0 + ROWS_PB, NN);
        int e_start = __builtin_amdgcn_readfirstlane(row_ptr[row0]);
        int e_end   = __builtin_amdgcn_readfirstlane(row_ptr[rend]);
        int nstage  = min(e_end - e_start, CAP);

        for (int t = threadIdx.x; t < nstage; t += 256) {
            uint2 m;
            m.x = (unsigned)adj_col[e_start + t];
            m.y = __float_as_uint(adj_vals[e_start + t]);
            meta[t] = m;
        }
        __syncthreads();

        int e0  = rv ? row_ptr[row] : 0;
        int cnt = rv ? row_ptr[row + 1] - e0 : 0;
        int eloc = e0 - e_start;
        float a0 = 0.f, a1 = 0.f, a2 = 0.f, a3 = 0.f;

        if (eloc + cnt <= nstage) {          // staged path (always, in practice)
            int body = cnt & ~(UN2 - 1);
            int k = 0;
            for (; k < body; k += UN2) {
                uint2 mm[UN2];
#pragma unroll
                for (int u = 0; u < UN2; ++u) mm[u] = meta[eloc + k + u];
                uint2 xv[UN2];
#pragma unroll
                for (int u = 0; u < UN2; ++u)
                    xv[u] = *(const uint2*)(xc + (size_t)mm[u].x * CH + i * 4);
#pragma unroll
                for (int u = 0; u < UN2; ++u) {
                    float v = __uint_as_float(mm[u].y);
                    a0 = fmaf(v, bf2f(xv[u].x & 0xFFFFu), a0);
                    a1 = fmaf(v, bf2f(xv[u].x >> 16),     a1);
                    a2 = fmaf(v, bf2f(xv[u].y & 0xFFFFu), a2);
                    a3 = fmaf(v, bf2f(xv[u].y >> 16),     a3);
                }
            }
            if (k < cnt) {                   // one clamped tail batch
#pragma unroll
                for (int u = 0; u < UN2; ++u) {
                    int kk = k + u;
                    uint2 m = meta[eloc + min(kk, cnt - 1)];
                    float v = (kk < cnt) ? __uint_as_float(m.y) : 0.f;
                    uint2 xv = *(const uint2*)(xc + (size_t)m.x * CH + i * 4);
                    a0 = fmaf(v, bf2f(xv.x & 0xFFFFu), a0);
                    a1 = fmaf(v, bf2f(xv.x >> 16),     a1);
                    a2 = fmaf(v, bf2f(xv.y & 0xFFFFu), a2);
                    a3 = fmaf(v, bf2f(xv.y >> 16),     a3);
                }
            }
        } else {                             // overflow fallback (correctness net)
            for (int k = 0; k < cnt; ++k) {
                int idx = e0 + k;
                float v = adj_vals[idx];
                int col = adj_col[idx];
                uint2 xv = *(const uint2*)(xc + (size_t)col * CH + i * 4);
                a0 = fmaf(v, bf2f(xv.x & 0xFFFFu), a0);
                a1 = fmaf(v, bf2f(xv.x >> 16),     a1);
                a2 = fmaf(v, bf2f(xv.y & 0xFFFFu), a2);
                a3 = fmaf(v, bf2f(xv.y >> 16),     a3);
            }
        }
        __syncthreads();                     // meta safe to overwrite next iter

        if (rv) {
            size_t off = (size_t)row * DD + c * CH + i * 4;
            const float* mp = drop_mask + off;
            float m0 = __builtin_nontemporal_load(mp);
            float m1 = __builtin_nontemporal_load(mp + 1);
            float m2 = __builtin_nontemporal_load(mp + 2);
            float m3 = __builtin_nontemporal_load(mp + 3);
            float h0 = fmaxf(a0, 0.f) * m0 * 2.f;
            float h1 = fmaxf(a1, 0.f) * m1 * 2.f;
            float h2 = fmaxf(a2, 0.f) * m2 * 2.f;
            float h3 = fmaxf(a3, 0.f) * m3 * 2.f;
            unsigned long long pk =
                (unsigned long long)((unsigned)f2bf(h0) | ((unsigned)f2bf(h1) << 16)) |
                ((unsigned long long)((unsigned)f2bf(h2) | ((unsigned)f2bf(h3) << 16)) << 32);
            __builtin_nontemporal_store(pk, (unsigned long long*)(hb + off));
        }
    }
}

// ---- Linear(256->40) as register-tiled GEMM: 64 rows/block, W in LDS ----
__global__ __launch_bounds__(256) void k_linear(
    const ushort* __restrict__ hb, const float* __restrict__ W,
    const float* __restrict__ b, float* __restrict__ z)
{
    __shared__ float ws[CC][DD + 4];
    int t = threadIdx.x;
    for (int idx = t; idx < CC * (DD / 4); idx += 256) {
        int c = idx >> 6, k4 = idx & 63;
        float4 v = ((const float4*)(W + (size_t)c * DD))[k4];
        float* p = &ws[c][k4 * 4];
        p[0] = v.x; p[1] = v.y; p[2] = v.z; p[3] = v.w;
    }
    __syncthreads();

    int row = blockIdx.x * LROWS + (t >> 2);
    int cg = (t & 3) * 10;
    if (row >= NN) return;

    const uint4* hrow = (const uint4*)(hb + (size_t)row * DD);
    float acc[10] = {0.f, 0.f, 0.f, 0.f, 0.f, 0.f, 0.f, 0.f, 0.f, 0.f};

    for (int k8 = 0; k8 < DD / 8; ++k8) {           // 8 dims per iter
        uint4 hv = hrow[k8];
        float h0 = bf2f(hv.x & 0xFFFFu), h1 = bf2f(hv.x >> 16);
        float h2 = bf2f(hv.y & 0xFFFFu), h3 = bf2f(hv.y >> 16);
        float h4 = bf2f(hv.z & 0xFFFFu), h5 = bf2f(hv.z >> 16);
        float h6 = bf2f(hv.w & 0xFFFFu), h7 = bf2f(hv.w >> 16);
#pragma unroll
        for (int j = 0; j < 10; ++j) {
            const float* wp = &ws[cg + j][k8 * 8];
            float4 wa = *(const float4*)wp;
            float4 wb = *(const float4*)(wp + 4);
            acc[j] = fmaf(h0, wa.x, fmaf(h1, wa.y,
                     fmaf(h2, wa.z, fmaf(h3, wa.w, acc[j]))));
            acc[j] = fmaf(h4, wb.x, fmaf(h5, wb.y,
                     fmaf(h6, wb.z, fmaf(h7, wb.w, acc[j]))));
        }
    }
#pragma unroll
    for (int j = 0; j < 10; ++j)
        z[(size_t)row * CC + cg + j] = acc[j] + b[cg + j];
}

// ---------------- out = SpMM(z), z [NN,40] f32 (cache-hot) ----------------
__global__ __launch_bounds__(256) void k_spmm2(
    const float* __restrict__ z, const float* __restrict__ adj_vals,
    const int* __restrict__ adj_col, const int* __restrict__ row_ptr,
    float* __restrict__ out)
{
    int wave = threadIdx.x >> 6;
    int lane = threadIdx.x & 63;
    int row = blockIdx.x * 4 + wave;
    int cl = lane < CC ? lane : CC - 1;

    int e0 = __builtin_amdgcn_readfirstlane(row_ptr[row]);
    int e1 = __builtin_amdgcn_readfirstlane(row_ptr[row + 1]);

    float acc = 0.f;
    int nb = (e1 - e0 + UN2 - 1) / UN2;
    for (int bI = 0; bI < nb; ++bI) {
        int base = e0 + bI * UN2;
        float vv[UN2]; int cc[UN2];
#pragma unroll
        for (int u = 0; u < UN2; ++u) {
            int idx = base + u;
            bool ok = idx < e1;
            idx = ok ? idx : e1 - 1;
            vv[u] = ok ? adj_vals[idx] : 0.f;
            cc[u] = adj_col[idx];
        }
        float za[UN2];
#pragma unroll
        for (int u = 0; u < UN2; ++u)
            za[u] = z[(size_t)cc[u] * CC + cl];
#pragma unroll
        for (int u = 0; u < UN2; ++u)
            acc = fmaf(vv[u], za[u], acc);
    }
    if (lane < CC) out[(size_t)row * CC + lane] = acc;
}

extern "C" void kernel_launch(void* const* d_in, const int* in_sizes, int n_in,
                              void* d_out, int out_size, void* d_ws, size_t ws_size,
                              hipStream_t stream) {
    const float* x         = (const float*)d_in[0];
    const float* adj_vals  = (const float*)d_in[1];
    const float* W         = (const float*)d_in[2];
    const float* b         = (const float*)d_in[3];
    const float* drop_mask = (const float*)d_in[4];
    const int*   adj_row   = (const int*)d_in[5];
    const int*   adj_col   = (const int*)d_in[6];
    float* out = (float*)d_out;

    // ws: row_ptr | z | xb[16][NN][16] | hb[NN][256]   (~119 MB)
    char* wsp = (char*)d_ws;
    size_t rp_bytes = ((size_t)(NN + 1) * 4 + 255) & ~(size_t)255;
    size_t z_bytes  = (size_t)NN * CC * 4;
    size_t xb_bytes = (size_t)NN * DD * 2;
    int* row_ptr = (int*)wsp;
    float* zbuf  = (float*)(wsp + rp_bytes);
    ushort* xb   = (ushort*)(wsp + rp_bytes + z_bytes);
    ushort* hb   = (ushort*)(wsp + rp_bytes + z_bytes + xb_bytes);

    hipLaunchKernelGGL(k_row_ptr, dim3((EE + 255) / 256), dim3(256), 0, stream,
                       adj_row, row_ptr);
    hipLaunchKernelGGL(k_cvt_t, dim3(NN / 32), dim3(256), 0, stream, x, xb);
    hipLaunchKernelGGL(k_chunk, dim3(CHUNK_BLOCKS), dim3(256), 0, stream,
                       xb, adj_vals, adj_col, row_ptr, drop_mask, hb);
    hipLaunchKernelGGL(k_linear, dim3((NN + LROWS - 1) / LROWS), dim3(256), 0,
                       stream, hb, W, b, zbuf);
    hipLaunchKernelGGL(k_spmm2, dim3(NN / 4), dim3(256), 0, stream,
                       zbuf, adj_vals, adj_col, row_ptr, out);
}

// Round 10
// 465.913 us; speedup vs baseline: 4.3826x; 1.1840x over previous
//
#include <hip/hip_runtime.h>

#define NN 100000
#define EE 3200000
#define DD 256
#define CC 40
#define NCH 8
#define CH 32
#define UN2 8

#define CAP 2432              // staged edges per 64-row group (avg 2048, +8.5 sigma)
#define ROWS_PB 64
#define COHORT 256            // blocks per chunk
#define CHUNK_BLOCKS (COHORT * 8)
#define RG64 1563             // ceil(NN / 64)
#define LROWS 64              // rows per k_linear block

__device__ __forceinline__ float bf2f(unsigned int u) {
    return __uint_as_float(u << 16);
}
__device__ __forceinline__ unsigned short f2bf(float f) {
    unsigned int t = __float_as_uint(f);
    return (unsigned short)((t + 0x7FFFu + ((t >> 16) & 1u)) >> 16);
}

// ---------------- CSR row_ptr from sorted adj_row ----------------
__global__ __launch_bounds__(256) void k_row_ptr(const int* __restrict__ adj_row,
                                                 int* __restrict__ row_ptr) {
    int e = blockIdx.x * 256 + threadIdx.x;
    if (e >= EE) return;
    int r = adj_row[e];
    int prev = (e == 0) ? -1 : adj_row[e - 1];
    for (int rr = prev + 1; rr <= r; ++rr) row_ptr[rr] = e;
    if (e == EE - 1) {
        for (int rr = r + 1; rr <= NN; ++rr) row_ptr[rr] = EE;
    }
}

// ---- x[NN][256] f32 -> xb[8][NN][32] bf16, LDS transpose, coalesced IO ----
__global__ __launch_bounds__(256) void k_cvt_t(const float* __restrict__ x,
                                               ushort* __restrict__ xb) {
    __shared__ ushort ls[32][DD + 4];
    int t = threadIdx.x;
    size_t r0 = (size_t)blockIdx.x * 32;
    const float4* src = (const float4*)(x + r0 * DD);
#pragma unroll
    for (int u = 0; u < 8; ++u) {
        int idx = u * 256 + t;
        float4 v = src[idx];
        int row = idx >> 6, d4 = idx & 63;
        ushort* p = &ls[row][d4 * 4];
        p[0] = f2bf(v.x); p[1] = f2bf(v.y); p[2] = f2bf(v.z); p[3] = f2bf(v.w);
    }
    __syncthreads();
    // thread t: chunk c = t>>5 (0..7), row r = t&31; write 64B contiguous.
    int c = t >> 5, r = t & 31;
    const uint4* s = (const uint4*)&ls[r][c * CH];
    uint4* dst = (uint4*)(xb + ((size_t)c * NN + r0 + r) * CH);
    dst[0] = s[0];
    dst[1] = s[1];
    dst[2] = s[2];
    dst[3] = s[3];
}

// ---- chunked SpMM1 + relu + dropout -> hb, reduction-free, LDS metadata ----
// 8 chunks of 32 dims; chunk c = bid&7 pinned to its XCD for the WHOLE kernel
// (single phase). Wave = 16 rows x 4 dim-lanes; lane gathers 16B (8 dims) of
// its row's x-chunk -> 1KB per gather instruction, no cross-lane reduction.
__global__ __launch_bounds__(256, 7) void k_chunk(
    const ushort* __restrict__ xb, const float* __restrict__ adj_vals,
    const int* __restrict__ adj_col, const int* __restrict__ row_ptr,
    const float* __restrict__ drop_mask, ushort* __restrict__ hb)
{
    __shared__ uint2 meta[CAP + 8];
    int bid = blockIdx.x;
    int c = bid & 7;
    int q = bid >> 3;
    int wave = threadIdx.x >> 6, lane = threadIdx.x & 63;
    int g = lane >> 2, i = lane & 3;        // row-in-16, dim-octet
    const ushort* xc = xb + (size_t)c * NN * CH;

    for (int rg = q; rg < RG64; rg += COHORT) {
        int row0 = rg * ROWS_PB;
        int row  = row0 + wave * 16 + g;
        bool rv  = row < NN;
        int rend = min(row0 + ROWS_PB, NN);
        int e_start = __builtin_amdgcn_readfirstlane(row_ptr[row0]);
        int e_end   = __builtin_amdgcn_readfirstlane(row_ptr[rend]);
        int nstage  = min(e_end - e_start, CAP);

        for (int t = threadIdx.x; t < nstage; t += 256) {
            uint2 m;
            m.x = (unsigned)adj_col[e_start + t];
            m.y = __float_as_uint(adj_vals[e_start + t]);
            meta[t] = m;
        }
        __syncthreads();

        int e0  = rv ? row_ptr[row] : 0;
        int cnt = rv ? row_ptr[row + 1] - e0 : 0;
        int eloc = e0 - e_start;
        float a0 = 0.f, a1 = 0.f, a2 = 0.f, a3 = 0.f;
        float a4 = 0.f, a5 = 0.f, a6 = 0.f, a7 = 0.f;

        if (eloc + cnt <= nstage) {          // staged path (always, in practice)
            int body = cnt & ~(UN2 - 1);
            int k = 0;
            for (; k < body; k += UN2) {
                uint2 mm[UN2];
#pragma unroll
                for (int u = 0; u < UN2; ++u) mm[u] = meta[eloc + k + u];
                uint4 xv[UN2];
#pragma unroll
                for (int u = 0; u < UN2; ++u)
                    xv[u] = *(const uint4*)(xc + (size_t)mm[u].x * CH + i * 8);
#pragma unroll
                for (int u = 0; u < UN2; ++u) {
                    float v = __uint_as_float(mm[u].y);
                    a0 = fmaf(v, bf2f(xv[u].x & 0xFFFFu), a0);
                    a1 = fmaf(v, bf2f(xv[u].x >> 16),     a1);
                    a2 = fmaf(v, bf2f(xv[u].y & 0xFFFFu), a2);
                    a3 = fmaf(v, bf2f(xv[u].y >> 16),     a3);
                    a4 = fmaf(v, bf2f(xv[u].z & 0xFFFFu), a4);
                    a5 = fmaf(v, bf2f(xv[u].z >> 16),     a5);
                    a6 = fmaf(v, bf2f(xv[u].w & 0xFFFFu), a6);
                    a7 = fmaf(v, bf2f(xv[u].w >> 16),     a7);
                }
            }
            if (k < cnt) {                   // one clamped tail batch
#pragma unroll
                for (int u = 0; u < UN2; ++u) {
                    int kk = k + u;
                    uint2 m = meta[eloc + min(kk, cnt - 1)];
                    float v = (kk < cnt) ? __uint_as_float(m.y) : 0.f;
                    uint4 xv = *(const uint4*)(xc + (size_t)m.x * CH + i * 8);
                    a0 = fmaf(v, bf2f(xv.x & 0xFFFFu), a0);
                    a1 = fmaf(v, bf2f(xv.x >> 16),     a1);
                    a2 = fmaf(v, bf2f(xv.y & 0xFFFFu), a2);
                    a3 = fmaf(v, bf2f(xv.y >> 16),     a3);
                    a4 = fmaf(v, bf2f(xv.z & 0xFFFFu), a4);
                    a5 = fmaf(v, bf2f(xv.z >> 16),     a5);
                    a6 = fmaf(v, bf2f(xv.w & 0xFFFFu), a6);
                    a7 = fmaf(v, bf2f(xv.w >> 16),     a7);
                }
            }
        } else {                             // overflow fallback (correctness net)
            for (int k = 0; k < cnt; ++k) {
                int idx = e0 + k;
                float v = adj_vals[idx];
                int col = adj_col[idx];
                uint4 xv = *(const uint4*)(xc + (size_t)col * CH + i * 8);
                a0 = fmaf(v, bf2f(xv.x & 0xFFFFu), a0);
                a1 = fmaf(v, bf2f(xv.x >> 16),     a1);
                a2 = fmaf(v, bf2f(xv.y & 0xFFFFu), a2);
                a3 = fmaf(v, bf2f(xv.y >> 16),     a3);
                a4 = fmaf(v, bf2f(xv.z & 0xFFFFu), a4);
                a5 = fmaf(v, bf2f(xv.z >> 16),     a5);
                a6 = fmaf(v, bf2f(xv.w & 0xFFFFu), a6);
                a7 = fmaf(v, bf2f(xv.w >> 16),     a7);
            }
        }
        __syncthreads();                     // meta safe to overwrite next iter

        if (rv) {
            size_t off = (size_t)row * DD + c * CH + i * 8;
            const float* mp = drop_mask + off;
            float m0 = __builtin_nontemporal_load(mp);
            float m1 = __builtin_nontemporal_load(mp + 1);
            float m2 = __builtin_nontemporal_load(mp + 2);
            float m3 = __builtin_nontemporal_load(mp + 3);
            float m4 = __builtin_nontemporal_load(mp + 4);
            float m5 = __builtin_nontemporal_load(mp + 5);
            float m6 = __builtin_nontemporal_load(mp + 6);
            float m7 = __builtin_nontemporal_load(mp + 7);
            float h0 = fmaxf(a0, 0.f) * m0 * 2.f;
            float h1 = fmaxf(a1, 0.f) * m1 * 2.f;
            float h2 = fmaxf(a2, 0.f) * m2 * 2.f;
            float h3 = fmaxf(a3, 0.f) * m3 * 2.f;
            float h4 = fmaxf(a4, 0.f) * m4 * 2.f;
            float h5 = fmaxf(a5, 0.f) * m5 * 2.f;
            float h6 = fmaxf(a6, 0.f) * m6 * 2.f;
            float h7 = fmaxf(a7, 0.f) * m7 * 2.f;
            unsigned long long p0 =
                (unsigned long long)((unsigned)f2bf(h0) | ((unsigned)f2bf(h1) << 16)) |
                ((unsigned long long)((unsigned)f2bf(h2) | ((unsigned)f2bf(h3) << 16)) << 32);
            unsigned long long p1 =
                (unsigned long long)((unsigned)f2bf(h4) | ((unsigned)f2bf(h5) << 16)) |
                ((unsigned long long)((unsigned)f2bf(h6) | ((unsigned)f2bf(h7) << 16)) << 32);
            __builtin_nontemporal_store(p0, (unsigned long long*)(hb + off));
            __builtin_nontemporal_store(p1, (unsigned long long*)(hb + off + 4));
        }
    }
}

// ---- Linear(256->40) as register-tiled GEMM: 64 rows/block, W in LDS ----
__global__ __launch_bounds__(256) void k_linear(
    const ushort* __restrict__ hb, const float* __restrict__ W,
    const float* __restrict__ b, float* __restrict__ z)
{
    __shared__ float ws[CC][DD + 4];
    int t = threadIdx.x;
    for (int idx = t; idx < CC * (DD / 4); idx += 256) {
        int c = idx >> 6, k4 = idx & 63;
        float4 v = ((const float4*)(W + (size_t)c * DD))[k4];
        float* p = &ws[c][k4 * 4];
        p[0] = v.x; p[1] = v.y; p[2] = v.z; p[3] = v.w;
    }
    __syncthreads();

    int row = blockIdx.x * LROWS + (t >> 2);
    int cg = (t & 3) * 10;
    if (row >= NN) return;

    const uint4* hrow = (const uint4*)(hb + (size_t)row * DD);
    float acc[10] = {0.f, 0.f, 0.f, 0.f, 0.f, 0.f, 0.f, 0.f, 0.f, 0.f};

    for (int k8 = 0; k8 < DD / 8; ++k8) {           // 8 dims per iter
        uint4 hv = hrow[k8];
        float h0 = bf2f(hv.x & 0xFFFFu), h1 = bf2f(hv.x >> 16);
        float h2 = bf2f(hv.y & 0xFFFFu), h3 = bf2f(hv.y >> 16);
        float h4 = bf2f(hv.z & 0xFFFFu), h5 = bf2f(hv.z >> 16);
        float h6 = bf2f(hv.w & 0xFFFFu), h7 = bf2f(hv.w >> 16);
#pragma unroll
        for (int j = 0; j < 10; ++j) {
            const float* wp = &ws[cg + j][k8 * 8];
            float4 wa = *(const float4*)wp;
            float4 wb = *(const float4*)(wp + 4);
            acc[j] = fmaf(h0, wa.x, fmaf(h1, wa.y,
                     fmaf(h2, wa.z, fmaf(h3, wa.w, acc[j]))));
            acc[j] = fmaf(h4, wb.x, fmaf(h5, wb.y,
                     fmaf(h6, wb.z, fmaf(h7, wb.w, acc[j]))));
        }
    }
#pragma unroll
    for (int j = 0; j < 10; ++j)
        z[(size_t)row * CC + cg + j] = acc[j] + b[cg + j];
}

// ---------------- out = SpMM(z), z [NN,40] f32 (cache-hot) ----------------
__global__ __launch_bounds__(256) void k_spmm2(
    const float* __restrict__ z, const float* __restrict__ adj_vals,
    const int* __restrict__ adj_col, const int* __restrict__ row_ptr,
    float* __restrict__ out)
{
    int wave = threadIdx.x >> 6;
    int lane = threadIdx.x & 63;
    int row = blockIdx.x * 4 + wave;
    int cl = lane < CC ? lane : CC - 1;

    int e0 = __builtin_amdgcn_readfirstlane(row_ptr[row]);
    int e1 = __builtin_amdgcn_readfirstlane(row_ptr[row + 1]);

    float acc = 0.f;
    int nb = (e1 - e0 + UN2 - 1) / UN2;
    for (int bI = 0; bI < nb; ++bI) {
        int base = e0 + bI * UN2;
        float vv[UN2]; int cc[UN2];
#pragma unroll
        for (int u = 0; u < UN2; ++u) {
            int idx = base + u;
            bool ok = idx < e1;
            idx = ok ? idx : e1 - 1;
            vv[u] = ok ? adj_vals[idx] : 0.f;
            cc[u] = adj_col[idx];
        }
        float za[UN2];
#pragma unroll
        for (int u = 0; u < UN2; ++u)
            za[u] = z[(size_t)cc[u] * CC + cl];
#pragma unroll
        for (int u = 0; u < UN2; ++u)
            acc = fmaf(vv[u], za[u], acc);
    }
    if (lane < CC) out[(size_t)row * CC + lane] = acc;
}

extern "C" void kernel_launch(void* const* d_in, const int* in_sizes, int n_in,
                              void* d_out, int out_size, void* d_ws, size_t ws_size,
                              hipStream_t stream) {
    const float* x         = (const float*)d_in[0];
    const float* adj_vals  = (const float*)d_in[1];
    const float* W         = (const float*)d_in[2];
    const float* b         = (const float*)d_in[3];
    const float* drop_mask = (const float*)d_in[4];
    const int*   adj_row   = (const int*)d_in[5];
    const int*   adj_col   = (const int*)d_in[6];
    float* out = (float*)d_out;

    // ws: row_ptr | z | xb[8][NN][32] | hb[NN][256]   (~119 MB)
    char* wsp = (char*)d_ws;
    size_t rp_bytes = ((size_t)(NN + 1) * 4 + 255) & ~(size_t)255;
    size_t z_bytes  = (size_t)NN * CC * 4;
    size_t xb_bytes = (size_t)NN * DD * 2;
    int* row_ptr = (int*)wsp;
    float* zbuf  = (float*)(wsp + rp_bytes);
    ushort* xb   = (ushort*)(wsp + rp_bytes + z_bytes);
    ushort* hb   = (ushort*)(wsp + rp_bytes + z_bytes + xb_bytes);

    hipLaunchKernelGGL(k_row_ptr, dim3((EE + 255) / 256), dim3(256), 0, stream,
                       adj_row, row_ptr);
    hipLaunchKernelGGL(k_cvt_t, dim3(NN / 32), dim3(256), 0, stream, x, xb);
    hipLaunchKernelGGL(k_chunk, dim3(CHUNK_BLOCKS), dim3(256), 0, stream,
                       xb, adj_vals, adj_col, row_ptr, drop_mask, hb);
    hipLaunchKernelGGL(k_linear, dim3((NN + LROWS - 1) / LROWS), dim3(256), 0,
                       stream, hb, W, b, zbuf);
    hipLaunchKernelGGL(k_spmm2, dim3(NN / 4), dim3(256), 0, stream,
                       zbuf, adj_vals, adj_col, row_ptr, out);
}

// Round 11
// 445.189 us; speedup vs baseline: 4.5866x; 1.0466x over previous
//
#include <hip/hip_runtime.h>

#define NN 100000
#define EE 3200000
#define DD 256
#define CC 40
#define NCH 8
#define CH 32
#define UN2 8

#define CAPW 640              // staged edges per 16-row wave (avg 512, +5.7 sigma)
#define COHORT 256            // blocks per chunk
#define CHUNK_BLOCKS (COHORT * 8)
#define WPC (COHORT * 4)      // waves per chunk
#define WG16 (NN / 16)        // 6250 wave-groups of 16 rows
#define LROWS 64              // rows per k_linear block

__device__ __forceinline__ float bf2f(unsigned int u) {
    return __uint_as_float(u << 16);
}
__device__ __forceinline__ unsigned short f2bf(float f) {
    unsigned int t = __float_as_uint(f);
    return (unsigned short)((t + 0x7FFFu + ((t >> 16) & 1u)) >> 16);
}

// ---------------- CSR row_ptr from sorted adj_row ----------------
__global__ __launch_bounds__(256) void k_row_ptr(const int* __restrict__ adj_row,
                                                 int* __restrict__ row_ptr) {
    int e = blockIdx.x * 256 + threadIdx.x;
    if (e >= EE) return;
    int r = adj_row[e];
    int prev = (e == 0) ? -1 : adj_row[e - 1];
    for (int rr = prev + 1; rr <= r; ++rr) row_ptr[rr] = e;
    if (e == EE - 1) {
        for (int rr = r + 1; rr <= NN; ++rr) row_ptr[rr] = EE;
    }
}

// ---- x[NN][256] f32 -> xb[8][NN][32] bf16, LDS transpose, coalesced IO ----
__global__ __launch_bounds__(256) void k_cvt_t(const float* __restrict__ x,
                                               ushort* __restrict__ xb) {
    __shared__ ushort ls[32][DD + 4];
    int t = threadIdx.x;
    size_t r0 = (size_t)blockIdx.x * 32;
    const float4* src = (const float4*)(x + r0 * DD);
#pragma unroll
    for (int u = 0; u < 8; ++u) {
        int idx = u * 256 + t;
        float4 v = src[idx];
        int row = idx >> 6, d4 = idx & 63;
        ushort* p = &ls[row][d4 * 4];
        p[0] = f2bf(v.x); p[1] = f2bf(v.y); p[2] = f2bf(v.z); p[3] = f2bf(v.w);
    }
    __syncthreads();
    int c = t >> 5, r = t & 31;
    const uint4* s = (const uint4*)&ls[r][c * CH];
    uint4* dst = (uint4*)(xb + ((size_t)c * NN + r0 + r) * CH);
    dst[0] = s[0];
    dst[1] = s[1];
    dst[2] = s[2];
    dst[3] = s[3];
}

// ---- chunked SpMM1 + relu + dropout -> hb: per-WAVE staging, no barriers ----
// Chunk c = bid&7 pinned to its XCD. Each wave owns 16 contiguous rows and
// stages its own contiguous edge range into a private LDS slice; waves are
// fully independent (no __syncthreads). 8 blocks/CU (160KB LDS), 32 waves/CU.
__global__ __launch_bounds__(256, 8) void k_chunk(
    const ushort* __restrict__ xb, const float* __restrict__ adj_vals,
    const int* __restrict__ adj_col, const int* __restrict__ row_ptr,
    const float* __restrict__ drop_mask, ushort* __restrict__ hb)
{
    __shared__ uint2 meta[4][CAPW];
    int bid = blockIdx.x;
    int c = bid & 7;
    int q = bid >> 3;
    int wave = threadIdx.x >> 6, lane = threadIdx.x & 63;
    int g = lane >> 2, i = lane & 3;        // row-in-16, dim-octet
    const ushort* xc = xb + (size_t)c * NN * CH;
    uint2* mw = meta[wave];
    int gw0 = q * 4 + wave;                 // wave rank within chunk

    for (int wg = gw0; wg < WG16; wg += WPC) {
        int row0 = wg * 16;
        int row  = row0 + g;
        int e_start = __builtin_amdgcn_readfirstlane(row_ptr[row0]);
        int e_end   = __builtin_amdgcn_readfirstlane(row_ptr[row0 + 16]);
        int nstage  = min(e_end - e_start, CAPW);

        for (int t = lane; t < nstage; t += 64) {
            uint2 m;
            m.x = (unsigned)adj_col[e_start + t];
            m.y = __float_as_uint(adj_vals[e_start + t]);
            mw[t] = m;
        }
        asm volatile("s_waitcnt lgkmcnt(0)" ::: "memory");
        __builtin_amdgcn_wave_barrier();

        int e0  = row_ptr[row];
        int cnt = row_ptr[row + 1] - e0;
        int eloc = e0 - e_start;
        float a0 = 0.f, a1 = 0.f, a2 = 0.f, a3 = 0.f;
        float a4 = 0.f, a5 = 0.f, a6 = 0.f, a7 = 0.f;

        if (eloc + cnt <= nstage) {          // staged path (always, in practice)
            int body = cnt & ~(UN2 - 1);
            int k = 0;
            for (; k < body; k += UN2) {
                uint2 mm[UN2];
#pragma unroll
                for (int u = 0; u < UN2; ++u) mm[u] = mw[eloc + k + u];
                uint4 xv[UN2];
#pragma unroll
                for (int u = 0; u < UN2; ++u)
                    xv[u] = *(const uint4*)(xc + (size_t)mm[u].x * CH + i * 8);
#pragma unroll
                for (int u = 0; u < UN2; ++u) {
                    float v = __uint_as_float(mm[u].y);
                    a0 = fmaf(v, bf2f(xv[u].x & 0xFFFFu), a0);
                    a1 = fmaf(v, bf2f(xv[u].x >> 16),     a1);
                    a2 = fmaf(v, bf2f(xv[u].y & 0xFFFFu), a2);
                    a3 = fmaf(v, bf2f(xv[u].y >> 16),     a3);
                    a4 = fmaf(v, bf2f(xv[u].z & 0xFFFFu), a4);
                    a5 = fmaf(v, bf2f(xv[u].z >> 16),     a5);
                    a6 = fmaf(v, bf2f(xv[u].w & 0xFFFFu), a6);
                    a7 = fmaf(v, bf2f(xv[u].w >> 16),     a7);
                }
            }
            if (k < cnt) {                   // one clamped tail batch
#pragma unroll
                for (int u = 0; u < UN2; ++u) {
                    int kk = k + u;
                    uint2 m = mw[eloc + min(kk, cnt - 1)];
                    float v = (kk < cnt) ? __uint_as_float(m.y) : 0.f;
                    uint4 xv = *(const uint4*)(xc + (size_t)m.x * CH + i * 8);
                    a0 = fmaf(v, bf2f(xv.x & 0xFFFFu), a0);
                    a1 = fmaf(v, bf2f(xv.x >> 16),     a1);
                    a2 = fmaf(v, bf2f(xv.y & 0xFFFFu), a2);
                    a3 = fmaf(v, bf2f(xv.y >> 16),     a3);
                    a4 = fmaf(v, bf2f(xv.z & 0xFFFFu), a4);
                    a5 = fmaf(v, bf2f(xv.z >> 16),     a5);
                    a6 = fmaf(v, bf2f(xv.w & 0xFFFFu), a6);
                    a7 = fmaf(v, bf2f(xv.w >> 16),     a7);
                }
            }
        } else {                             // overflow fallback (correctness net)
            for (int k = 0; k < cnt; ++k) {
                int idx = e0 + k;
                float v = adj_vals[idx];
                int col = adj_col[idx];
                uint4 xv = *(const uint4*)(xc + (size_t)col * CH + i * 8);
                a0 = fmaf(v, bf2f(xv.x & 0xFFFFu), a0);
                a1 = fmaf(v, bf2f(xv.x >> 16),     a1);
                a2 = fmaf(v, bf2f(xv.y & 0xFFFFu), a2);
                a3 = fmaf(v, bf2f(xv.y >> 16),     a3);
                a4 = fmaf(v, bf2f(xv.z & 0xFFFFu), a4);
                a5 = fmaf(v, bf2f(xv.z >> 16),     a5);
                a6 = fmaf(v, bf2f(xv.w & 0xFFFFu), a6);
                a7 = fmaf(v, bf2f(xv.w >> 16),     a7);
            }
        }
        __builtin_amdgcn_wave_barrier();     // keep next staging after reads

        {
            size_t off = (size_t)row * DD + c * CH + i * 8;
            const float* mp = drop_mask + off;
            float m0 = __builtin_nontemporal_load(mp);
            float m1 = __builtin_nontemporal_load(mp + 1);
            float m2 = __builtin_nontemporal_load(mp + 2);
            float m3 = __builtin_nontemporal_load(mp + 3);
            float m4 = __builtin_nontemporal_load(mp + 4);
            float m5 = __builtin_nontemporal_load(mp + 5);
            float m6 = __builtin_nontemporal_load(mp + 6);
            float m7 = __builtin_nontemporal_load(mp + 7);
            float h0 = fmaxf(a0, 0.f) * m0 * 2.f;
            float h1 = fmaxf(a1, 0.f) * m1 * 2.f;
            float h2 = fmaxf(a2, 0.f) * m2 * 2.f;
            float h3 = fmaxf(a3, 0.f) * m3 * 2.f;
            float h4 = fmaxf(a4, 0.f) * m4 * 2.f;
            float h5 = fmaxf(a5, 0.f) * m5 * 2.f;
            float h6 = fmaxf(a6, 0.f) * m6 * 2.f;
            float h7 = fmaxf(a7, 0.f) * m7 * 2.f;
            unsigned long long p0 =
                (unsigned long long)((unsigned)f2bf(h0) | ((unsigned)f2bf(h1) << 16)) |
                ((unsigned long long)((unsigned)f2bf(h2) | ((unsigned)f2bf(h3) << 16)) << 32);
            unsigned long long p1 =
                (unsigned long long)((unsigned)f2bf(h4) | ((unsigned)f2bf(h5) << 16)) |
                ((unsigned long long)((unsigned)f2bf(h6) | ((unsigned)f2bf(h7) << 16)) << 32);
            __builtin_nontemporal_store(p0, (unsigned long long*)(hb + off));
            __builtin_nontemporal_store(p1, (unsigned long long*)(hb + off + 4));
        }
    }
}

// ---- Linear(256->40) as register-tiled GEMM: 64 rows/block, W in LDS ----
// z written as bf16 (8MB) so spmm2's gather working set halves.
__global__ __launch_bounds__(256) void k_linear(
    const ushort* __restrict__ hb, const float* __restrict__ W,
    const float* __restrict__ b, ushort* __restrict__ z)
{
    __shared__ float ws[CC][DD + 4];
    int t = threadIdx.x;
    for (int idx = t; idx < CC * (DD / 4); idx += 256) {
        int c = idx >> 6, k4 = idx & 63;
        float4 v = ((const float4*)(W + (size_t)c * DD))[k4];
        float* p = &ws[c][k4 * 4];
        p[0] = v.x; p[1] = v.y; p[2] = v.z; p[3] = v.w;
    }
    __syncthreads();

    int row = blockIdx.x * LROWS + (t >> 2);
    int cg = (t & 3) * 10;
    if (row >= NN) return;

    const uint4* hrow = (const uint4*)(hb + (size_t)row * DD);
    float acc[10] = {0.f, 0.f, 0.f, 0.f, 0.f, 0.f, 0.f, 0.f, 0.f, 0.f};

    for (int k8 = 0; k8 < DD / 8; ++k8) {           // 8 dims per iter
        uint4 hv = hrow[k8];
        float h0 = bf2f(hv.x & 0xFFFFu), h1 = bf2f(hv.x >> 16);
        float h2 = bf2f(hv.y & 0xFFFFu), h3 = bf2f(hv.y >> 16);
        float h4 = bf2f(hv.z & 0xFFFFu), h5 = bf2f(hv.z >> 16);
        float h6 = bf2f(hv.w & 0xFFFFu), h7 = bf2f(hv.w >> 16);
#pragma unroll
        for (int j = 0; j < 10; ++j) {
            const float* wp = &ws[cg + j][k8 * 8];
            float4 wa = *(const float4*)wp;
            float4 wb = *(const float4*)(wp + 4);
            acc[j] = fmaf(h0, wa.x, fmaf(h1, wa.y,
                     fmaf(h2, wa.z, fmaf(h3, wa.w, acc[j]))));
            acc[j] = fmaf(h4, wb.x, fmaf(h5, wb.y,
                     fmaf(h6, wb.z, fmaf(h7, wb.w, acc[j]))));
        }
    }
#pragma unroll
    for (int j = 0; j < 10; ++j)
        z[(size_t)row * CC + cg + j] = f2bf(acc[j] + b[cg + j]);
}

// ------------- out = SpMM(z), z [NN,40] bf16 (L2-friendly 8MB) -------------
__global__ __launch_bounds__(256) void k_spmm2(
    const ushort* __restrict__ z, const float* __restrict__ adj_vals,
    const int* __restrict__ adj_col, const int* __restrict__ row_ptr,
    float* __restrict__ out)
{
    int wave = threadIdx.x >> 6;
    int lane = threadIdx.x & 63;
    int row = blockIdx.x * 4 + wave;
    int cl = lane < CC ? lane : CC - 1;

    int e0 = __builtin_amdgcn_readfirstlane(row_ptr[row]);
    int e1 = __builtin_amdgcn_readfirstlane(row_ptr[row + 1]);

    float acc = 0.f;
    int nb = (e1 - e0 + UN2 - 1) / UN2;
    for (int bI = 0; bI < nb; ++bI) {
        int base = e0 + bI * UN2;
        float vv[UN2]; int cc[UN2];
#pragma unroll
        for (int u = 0; u < UN2; ++u) {
            int idx = base + u;
            bool ok = idx < e1;
            idx = ok ? idx : e1 - 1;
            vv[u] = ok ? adj_vals[idx] : 0.f;
            cc[u] = adj_col[idx];
        }
        float za[UN2];
#pragma unroll
        for (int u = 0; u < UN2; ++u)
            za[u] = bf2f((unsigned)z[(size_t)cc[u] * CC + cl]);
#pragma unroll
        for (int u = 0; u < UN2; ++u)
            acc = fmaf(vv[u], za[u], acc);
    }
    if (lane < CC) out[(size_t)row * CC + lane] = acc;
}

extern "C" void kernel_launch(void* const* d_in, const int* in_sizes, int n_in,
                              void* d_out, int out_size, void* d_ws, size_t ws_size,
                              hipStream_t stream) {
    const float* x         = (const float*)d_in[0];
    const float* adj_vals  = (const float*)d_in[1];
    const float* W         = (const float*)d_in[2];
    const float* b         = (const float*)d_in[3];
    const float* drop_mask = (const float*)d_in[4];
    const int*   adj_row   = (const int*)d_in[5];
    const int*   adj_col   = (const int*)d_in[6];
    float* out = (float*)d_out;

    // ws: row_ptr | z(bf16, padded slot) | xb[8][NN][32] | hb[NN][256]
    char* wsp = (char*)d_ws;
    size_t rp_bytes = ((size_t)(NN + 1) * 4 + 255) & ~(size_t)255;
    size_t z_bytes  = (size_t)NN * CC * 4;
    size_t xb_bytes = (size_t)NN * DD * 2;
    int* row_ptr = (int*)wsp;
    ushort* zbuf = (ushort*)(wsp + rp_bytes);
    ushort* xb   = (ushort*)(wsp + rp_bytes + z_bytes);
    ushort* hb   = (ushort*)(wsp + rp_bytes + z_bytes + xb_bytes);

    hipLaunchKernelGGL(k_row_ptr, dim3((EE + 255) / 256), dim3(256), 0, stream,
                       adj_row, row_ptr);
    hipLaunchKernelGGL(k_cvt_t, dim3(NN / 32), dim3(256), 0, stream, x, xb);
    hipLaunchKernelGGL(k_chunk, dim3(CHUNK_BLOCKS), dim3(256), 0, stream,
                       xb, adj_vals, adj_col, row_ptr, drop_mask, hb);
    hipLaunchKernelGGL(k_linear, dim3((NN + LROWS - 1) / LROWS), dim3(256), 0,
                       stream, hb, W, b, zbuf);
    hipLaunchKernelGGL(k_spmm2, dim3(NN / 4), dim3(256), 0, stream,
                       zbuf, adj_vals, adj_col, row_ptr, out);
}